// Round 9
// baseline (710.365 us; speedup 1.0000x reference)
//
#include <hip/hip_runtime.h>

// ---------------------------------------------------------------------------
// GNN forward (GraphSAGE x3 + jump + scorer), N=100000, E=1600000, H=128.
// Round 9: round-5 structure + src-BUCKETED CSR (16 buckets of 8192 nodes,
// counting-sort via the existing rank atomic). The fused gather sweeps
// buckets in order -> ~2.1MB working set per phase -> L2-resident.
// NT loads/stores reverted (r8 regression: broke L1/L2 dup-read broadcast).
// ---------------------------------------------------------------------------

#define HDIM 128

using f16x8 = __attribute__((ext_vector_type(8))) _Float16;
using f32x4 = __attribute__((ext_vector_type(4))) float;

__device__ inline unsigned pack_f16x2(float a, float b) {
  _Float16 ha = (_Float16)a, hb = (_Float16)b;
  unsigned short ua = __builtin_bit_cast(unsigned short, ha);
  unsigned short ub = __builtin_bit_cast(unsigned short, hb);
  return (unsigned)ua | ((unsigned)ub << 16);
}
__device__ inline float2 unpack_f16x2(unsigned u) {
  _Float16 lo = __builtin_bit_cast(_Float16, (unsigned short)(u & 0xffffu));
  _Float16 hi = __builtin_bit_cast(_Float16, (unsigned short)(u >> 16));
  return make_float2((float)lo, (float)hi);
}

__device__ inline int src_bucket(int s) {
  int b = s >> 13;
  return (b > 15) ? 15 : b;
}

// --- bucketed in-degree count; atomic return = rank within (dst,bucket) ----
__global__ __launch_bounds__(256) void count_kernel(
    const int* __restrict__ src, const int* __restrict__ dst,
    int* __restrict__ cnt16, int* __restrict__ rank, int E) {
  int e = blockIdx.x * 256 + threadIdx.x;
  if (e >= E) return;
  int d = dst[e];
  int s = src[e];
  rank[e] = atomicAdd(&cnt16[((size_t)d << 4) + src_bucket(s)], 1);
}

// --- scan stage A: per-2048-chunk sums over M=16N ---------------------------
__global__ __launch_bounds__(256) void scan_block_sum2048(
    const int* __restrict__ a, int* __restrict__ bsum, int M) {
  __shared__ int sd[256];
  int t = threadIdx.x;
  int base = blockIdx.x * 2048 + t * 8;
  int s = 0;
#pragma unroll
  for (int j = 0; j < 8; ++j) {
    int i = base + j;
    s += (i < M) ? a[i] : 0;
  }
  sd[t] = s;
  __syncthreads();
  for (int off = 128; off > 0; off >>= 1) {
    if (t < off) sd[t] += sd[t + off];
    __syncthreads();
  }
  if (t == 0) bsum[blockIdx.x] = sd[0];
}

// --- scan stage B: exclusive scan of chunk sums (nch <= 1024) --------------
__global__ __launch_bounds__(256) void scan_partials(
    const int* __restrict__ bsum, int* __restrict__ boff, int nch) {
  __shared__ int sd[256];
  int t = threadIdx.x;
  int base = t * 4;
  int v0 = (base + 0 < nch) ? bsum[base + 0] : 0;
  int v1 = (base + 1 < nch) ? bsum[base + 1] : 0;
  int v2 = (base + 2 < nch) ? bsum[base + 2] : 0;
  int v3 = (base + 3 < nch) ? bsum[base + 3] : 0;
  sd[t] = v0 + v1 + v2 + v3;
  __syncthreads();
  for (int off = 1; off < 256; off <<= 1) {
    int x = sd[t];
    int y = (t >= off) ? sd[t - off] : 0;
    __syncthreads();
    sd[t] = x + y;
    __syncthreads();
  }
  int run = (t == 0) ? 0 : sd[t - 1];
  if (base + 0 < nch) boff[base + 0] = run; run += v0;
  if (base + 1 < nch) boff[base + 1] = run; run += v1;
  if (base + 2 < nch) boff[base + 2] = run; run += v2;
  if (base + 3 < nch) boff[base + 3] = run;
}

// --- scan stage C: per-element exclusive offsets over M=16N ----------------
__global__ __launch_bounds__(256) void scan_final2048(
    const int* __restrict__ a, const int* __restrict__ boff,
    int* __restrict__ outp, int M) {
  __shared__ int sd[256];
  int t = threadIdx.x;
  int base = blockIdx.x * 2048 + t * 8;
  int v[8];
  int s = 0;
#pragma unroll
  for (int j = 0; j < 8; ++j) {
    int i = base + j;
    v[j] = (i < M) ? a[i] : 0;
    s += v[j];
  }
  sd[t] = s;
  __syncthreads();
  for (int off = 1; off < 256; off <<= 1) {
    int x = sd[t];
    int y = (t >= off) ? sd[t - off] : 0;
    __syncthreads();
    sd[t] = x + y;
    __syncthreads();
  }
  int run = boff[blockIdx.x] + ((t == 0) ? 0 : sd[t - 1]);
#pragma unroll
  for (int j = 0; j < 8; ++j) {
    int i = base + j;
    if (i < M) outp[i] = run;
    run += v[j];
  }
}

// --- row metadata: cnt[i] = degree; seal rs16[16N] = E ---------------------
__global__ __launch_bounds__(256) void rowmeta_kernel(
    int* __restrict__ rs16, int* __restrict__ cnt, int N, int E) {
  int i = blockIdx.x * 256 + threadIdx.x;
  if (i >= N) return;
  int start = rs16[(size_t)i << 4];
  int end = (i == N - 1) ? E : rs16[((size_t)i << 4) + 16];
  cnt[i] = end - start;
  if (i == N - 1) rs16[(size_t)N << 4] = E;
}

// --- CSR fill, NO atomics: pos = rs16[d*16+bucket] + rank ------------------
__global__ __launch_bounds__(256) void fill_kernel(
    const int* __restrict__ src, const int* __restrict__ dst,
    const float* __restrict__ ea, const int* __restrict__ rs16,
    const int* __restrict__ rank, uint2* __restrict__ cidx2, int E) {
  int e = blockIdx.x * 256 + threadIdx.x;
  if (e >= E) return;
  int d = dst[e];
  int s = src[e];
  float2 v = *reinterpret_cast<const float2*>(&ea[2 * (size_t)e]);
  int pos = rs16[((size_t)d << 4) + src_bucket(s)] + rank[e];
  cidx2[pos] = make_uint2((unsigned)s, pack_f16x2(v.x, v.y));
}

// --- layer-0 x-space aggregation + edge-attr sum ---------------------------
__global__ __launch_bounds__(256) void aggx_kernel(
    const float* __restrict__ x, const int* __restrict__ rs16,
    const int* __restrict__ cnt, const uint2* __restrict__ cidx2,
    float* __restrict__ aggx, float* __restrict__ eagg, int N) {
  int i = blockIdx.x * 256 + threadIdx.x;
  if (i >= N) return;
  float4 a = *reinterpret_cast<const float4*>(&x[(size_t)i * 4]);
  float4 b = make_float4(0.f, 0.f, 0.f, 0.f);
  float e0 = 0.f, e1 = 0.f, f0 = 0.f, f1 = 0.f;
  int p = rs16[(size_t)i << 4], e = p + cnt[i];
  for (; p + 1 < e; p += 2) {
    uint2 c0 = cidx2[p], c1 = cidx2[p + 1];
    float4 v0 = *reinterpret_cast<const float4*>(&x[(size_t)c0.x * 4]);
    float4 v1 = *reinterpret_cast<const float4*>(&x[(size_t)c1.x * 4]);
    float2 u0 = unpack_f16x2(c0.y);
    float2 u1 = unpack_f16x2(c1.y);
    a.x += v0.x; a.y += v0.y; a.z += v0.z; a.w += v0.w;
    b.x += v1.x; b.y += v1.y; b.z += v1.z; b.w += v1.w;
    e0 += u0.x; e1 += u0.y;
    f0 += u1.x; f1 += u1.y;
  }
  if (p < e) {
    uint2 c0 = cidx2[p];
    float4 v0 = *reinterpret_cast<const float4*>(&x[(size_t)c0.x * 4]);
    float2 u0 = unpack_f16x2(c0.y);
    a.x += v0.x; a.y += v0.y; a.z += v0.z; a.w += v0.w;
    e0 += u0.x; e1 += u0.y;
  }
  a.x += b.x; a.y += b.y; a.z += b.z; a.w += b.w;
  *reinterpret_cast<float4*>(&aggx[(size_t)i * 4]) = a;
  eagg[2 * (size_t)i + 0] = e0 + f0;
  eagg[2 * (size_t)i + 1] = e1 + f1;
}

// --- pack GEMM weights into MFMA-frag-contiguous f16 layout ----------------
__global__ __launch_bounds__(256) void pack_weights_kernel(
    const float* __restrict__ Wn0, const float* __restrict__ Ws0,
    const float* __restrict__ Wn1, const float* __restrict__ Ws1,
    const float* __restrict__ Wn2, const float* __restrict__ Ws2,
    const float* __restrict__ Wj, _Float16* __restrict__ outp) {
  int i = blockIdx.x * 256 + threadIdx.x;
  if (i >= 147456) return;
  int j = i & 7, lane = (i >> 3) & 63;
  float v;
  if (i < 98304) {
    int l = i >> 15;
    int r = i & 32767;
    int nt = (r >> 9) & 7, kt = r >> 12;
    int k = kt * 32 + (lane >> 4) * 8 + j;
    int n = nt * 16 + (lane & 15);
    const float* Wn = (l == 0) ? Wn0 : (l == 1) ? Wn1 : Wn2;
    const float* Ws = (l == 0) ? Ws0 : (l == 1) ? Ws1 : Ws2;
    v = (k < 128) ? Wn[(size_t)k * HDIM + n] : Ws[(size_t)(k - 128) * HDIM + n];
  } else {
    int r = i - 98304;
    int nt = (r >> 9) & 7, kt = r >> 12;  // kt 0..11
    int k = kt * 32 + (lane >> 4) * 8 + j;
    int n = nt * 16 + (lane & 15);
    v = Wj[(size_t)k * HDIM + n];
  }
  outp[i] = (_Float16)v;
}

// --- fused SAGE layer on MFMA (bucketed gather fused for L != 0) -----------
template <bool L0>
__global__ __launch_bounds__(256) void sage_mfma_kernel(
    const float* __restrict__ A0f, const float* __restrict__ A1f,
    const _Float16* __restrict__ Hprev, const int* __restrict__ rs16,
    const uint2* __restrict__ cidx2,
    const float* __restrict__ Wi, const float* __restrict__ bi,
    const float* __restrict__ eagg, const int* __restrict__ cnt,
    const _Float16* __restrict__ Bp, const float* __restrict__ Wn,
    _Float16* __restrict__ outh, float* __restrict__ bnstat, int N) {
  __shared__ _Float16 sA[64 * 256];  // 32 KB, XOR-swizzled rows
  __shared__ float sE[128];          // e0,e1 per row (pre-scaled)
  __shared__ float sBNs[4][128];
  __shared__ float sBNq[4][128];
  const int t = threadIdx.x;
  const int base = blockIdx.x * 64;

  if (t < 64) {
    int grow = base + t;
    float e0 = 0.f, e1 = 0.f;
    if (grow < N) {
      float inv = 1.0f / ((float)cnt[grow] + 1.0f);
      e0 = eagg[2 * (size_t)grow] * inv;
      e1 = eagg[2 * (size_t)grow + 1] * inv;
    }
    sE[2 * t] = e0;
    sE[2 * t + 1] = e1;
  }

  if (L0) {
    // stage A tile from x-space projections
#pragma unroll
    for (int it = 0; it < 8; ++it) {
      int c = t + it * 256;
      int row = c >> 5, k8 = c & 31;
      int grow = base + row;
      f16x8 hv = {};
      if (grow < N) {
        float inv = 1.0f / ((float)cnt[grow] + 1.0f);
        float scale = (k8 < 16) ? inv : 1.0f;
        const float* rp = (k8 < 16) ? &A0f[(size_t)grow * 4] : &A1f[(size_t)grow * 4];
        float4 r = *reinterpret_cast<const float4*>(rp);
        int col0 = (k8 & 15) * 8;
#pragma unroll
        for (int jj = 0; jj < 8; ++jj) {
          int col = col0 + jj;
          hv[jj] = (_Float16)(bi[col] + scale * (r.x * Wi[col] + r.y * Wi[HDIM + col] +
                                                 r.z * Wi[2 * HDIM + col] + r.w * Wi[3 * HDIM + col]));
        }
      }
      int byte = (row * 512 + k8 * 16) ^ ((row & 7) << 4);
      *reinterpret_cast<f16x8*>(reinterpret_cast<char*>(sA) + byte) = hv;
    }
  } else {
    // fused bucketed gather: thread t -> row t>>2, column quarter q = t&3
    const int row = t >> 2, q = t & 3;
    const int grow = base + row;
    float acc[32];
#pragma unroll
    for (int c = 0; c < 32; ++c) acc[c] = 0.f;
    f16x8 selfv[4] = {};
    if (grow < N) {
      const f16x8* selfp = reinterpret_cast<const f16x8*>(Hprev + (size_t)grow * HDIM) + q * 4;
#pragma unroll
      for (int j = 0; j < 4; ++j) {
        selfv[j] = selfp[j];
#pragma unroll
        for (int jj = 0; jj < 8; ++jj) acc[j * 8 + jj] = (float)selfv[j][jj];
      }
      const int rbase = grow << 4;
      int p = rs16[rbase];
      // sweep buckets in ascending src order (L2-resident phases)
      for (int b = 1; b <= 16; ++b) {
        int pe = rs16[rbase + b];
        for (; p + 1 < pe; p += 2) {
          uint2 q0 = cidx2[p], q1 = cidx2[p + 1];
          const f16x8* m0 = reinterpret_cast<const f16x8*>(Hprev + (size_t)q0.x * HDIM) + q * 4;
          const f16x8* m1 = reinterpret_cast<const f16x8*>(Hprev + (size_t)q1.x * HDIM) + q * 4;
          f16x8 c0[4], c1[4];
#pragma unroll
          for (int j = 0; j < 4; ++j) c0[j] = m0[j];
#pragma unroll
          for (int j = 0; j < 4; ++j) c1[j] = m1[j];
#pragma unroll
          for (int j = 0; j < 4; ++j)
#pragma unroll
            for (int jj = 0; jj < 8; ++jj)
              acc[j * 8 + jj] += (float)c0[j][jj] + (float)c1[j][jj];
        }
        if (p < pe) {
          uint2 q0 = cidx2[p];
          const f16x8* m0 = reinterpret_cast<const f16x8*>(Hprev + (size_t)q0.x * HDIM) + q * 4;
#pragma unroll
          for (int j = 0; j < 4; ++j) {
            f16x8 c0 = m0[j];
#pragma unroll
            for (int jj = 0; jj < 8; ++jj) acc[j * 8 + jj] += (float)c0[jj];
          }
          p = pe;
        }
      }
      float inv = 1.0f / ((float)cnt[grow] + 1.0f);
#pragma unroll
      for (int c = 0; c < 32; ++c) acc[c] *= inv;
    }
    const int swz = (row & 7) << 4;
#pragma unroll
    for (int j = 0; j < 4; ++j) {
      f16x8 av;
#pragma unroll
      for (int jj = 0; jj < 8; ++jj) av[jj] = (_Float16)acc[j * 8 + jj];
      int k8a = q * 4 + j;
      *reinterpret_cast<f16x8*>(reinterpret_cast<char*>(sA) +
                                ((row * 512 + k8a * 16) ^ swz)) = av;
      int k8h = 16 + q * 4 + j;
      *reinterpret_cast<f16x8*>(reinterpret_cast<char*>(sA) +
                                ((row * 512 + k8h * 16) ^ swz)) = selfv[j];
    }
  }
  __syncthreads();

  const int lane = t & 63;
  const int w = t >> 6;
  const int col16 = lane & 15;
  const int kgrp = lane >> 4;
  f32x4 acc[8];
#pragma unroll
  for (int nt = 0; nt < 8; ++nt) acc[nt] = (f32x4){0.f, 0.f, 0.f, 0.f};

  const int arow = w * 16 + col16;
  const int aswz = (arow & 7) << 4;
#pragma unroll
  for (int kt = 0; kt < 8; ++kt) {
    int abyte = (arow * 512 + kt * 64 + kgrp * 16) ^ aswz;
    f16x8 a = *reinterpret_cast<const f16x8*>(reinterpret_cast<const char*>(sA) + abyte);
    const f16x8* bp = reinterpret_cast<const f16x8*>(Bp) + (size_t)kt * 512 + lane;
#pragma unroll
    for (int nt = 0; nt < 8; ++nt) {
      f16x8 b = bp[nt * 64];
      acc[nt] = __builtin_amdgcn_mfma_f32_16x16x32_f16(a, b, acc[nt], 0, 0, 0);
    }
  }

  // epilogue: edge-attr rank-2 update + relu + f16 store + BN partials
#pragma unroll
  for (int nt = 0; nt < 8; ++nt) {
    int col = nt * 16 + col16;
    float we0 = Wn[(size_t)128 * HDIM + col];
    float we1 = Wn[(size_t)129 * HDIM + col];
    float s = 0.f, q = 0.f;
#pragma unroll
    for (int i = 0; i < 4; ++i) {
      int lr = w * 16 + kgrp * 4 + i;
      int row = base + lr;
      if (row < N) {
        float v = acc[nt][i] + sE[2 * lr] * we0 + sE[2 * lr + 1] * we1;
        v = fmaxf(v, 0.f);
        outh[(size_t)row * HDIM + col] = (_Float16)v;
        s += v;
        q += v * v;
      }
    }
    s += __shfl_xor(s, 16, 64);
    s += __shfl_xor(s, 32, 64);
    q += __shfl_xor(q, 16, 64);
    q += __shfl_xor(q, 32, 64);
    if (lane < 16) {
      sBNs[w][col] = s;
      sBNq[w][col] = q;
    }
  }
  __syncthreads();
  if (t < 128) {
    float s = sBNs[0][t] + sBNs[1][t] + sBNs[2][t] + sBNs[3][t];
    float q = sBNq[0][t] + sBNq[1][t] + sBNq[2][t] + sBNq[3][t];
    atomicAdd(&bnstat[t], s);
    atomicAdd(&bnstat[HDIM + t], q);
  }
}

// --- BN finalize (in-block) + apply + L2 normalize: f16 in, f16 out --------
__global__ __launch_bounds__(256) void bn_l2_kernel(
    const _Float16* __restrict__ outh, const float* __restrict__ stat,
    const float* __restrict__ gamma, const float* __restrict__ beta,
    float invN, _Float16* __restrict__ h, int N) {
  __shared__ float sAB[256];
  int t = threadIdx.x;
  if (t < 128) {
    float mean = stat[t] * invN;
    float var = stat[128 + t] * invN - mean * mean;
    float A = gamma[t] / sqrtf(var + 1e-5f);
    sAB[t] = A;
    sAB[128 + t] = beta[t] - mean * A;
  }
  __syncthreads();
  int i = blockIdx.x * 4 + (t >> 6);
  if (i >= N) return;
  int lane = t & 63;
  unsigned u = (reinterpret_cast<const unsigned*>(outh + (size_t)i * HDIM))[lane];
  float2 v = unpack_f16x2(u);
  float A0 = sAB[lane * 2 + 0], A1 = sAB[lane * 2 + 1];
  float B0 = sAB[128 + lane * 2 + 0], B1 = sAB[128 + lane * 2 + 1];
  float y0 = v.x * A0 + B0;
  float y1 = v.y * A1 + B1;
  float s = y0 * y0 + y1 * y1;
#pragma unroll
  for (int m = 32; m > 0; m >>= 1) s += __shfl_xor(s, m, 64);
  float inv = 1.0f / fmaxf(sqrtf(s), 1e-12f);
  (reinterpret_cast<unsigned*>(h + (size_t)i * HDIM))[lane] =
      pack_f16x2(y0 * inv, y1 * inv);
}

// --- jump GEMM (MFMA, K=384, f16 h inputs) + scorer MLP --------------------
__global__ __launch_bounds__(256) void jump_mfma_kernel(
    const _Float16* __restrict__ h1, const _Float16* __restrict__ h2,
    const _Float16* __restrict__ h3, const _Float16* __restrict__ Bp,
    const float* __restrict__ bj, const float* __restrict__ W1p,
    const float* __restrict__ b1p, const float* __restrict__ W2p,
    const float* __restrict__ b2p, float* __restrict__ outp, int N) {
  __shared__ _Float16 sA[64 * 384];  // 48 KB; reused: sG[64*128] f32 + sS[64*64] f32
  const int t = threadIdx.x;
  const int base = blockIdx.x * 64;

  const _Float16* hs[3] = {h1, h2, h3};
#pragma unroll
  for (int it = 0; it < 12; ++it) {
    int c = t + it * 256;
    int row = c / 48, k8 = c % 48;
    int grow = base + row;
    f16x8 hv = {};
    if (grow < N)
      hv = (reinterpret_cast<const f16x8*>(hs[k8 >> 4] + (size_t)grow * HDIM))[k8 & 15];
    int byte = (row * 768 + k8 * 16) ^ ((row & 7) << 4);
    *reinterpret_cast<f16x8*>(reinterpret_cast<char*>(sA) + byte) = hv;
  }
  __syncthreads();

  const int lane = t & 63;
  const int w = t >> 6;
  const int col16 = lane & 15;
  const int kgrp = lane >> 4;
  f32x4 acc[8];
#pragma unroll
  for (int nt = 0; nt < 8; ++nt) acc[nt] = (f32x4){0.f, 0.f, 0.f, 0.f};

  const int arow = w * 16 + col16;
  const int aswz = (arow & 7) << 4;
#pragma unroll
  for (int kt = 0; kt < 12; ++kt) {
    int abyte = (arow * 768 + kt * 64 + kgrp * 16) ^ aswz;
    f16x8 a = *reinterpret_cast<const f16x8*>(reinterpret_cast<const char*>(sA) + abyte);
    const f16x8* bp = reinterpret_cast<const f16x8*>(Bp) + (size_t)kt * 512 + lane;
#pragma unroll
    for (int nt = 0; nt < 8; ++nt) {
      f16x8 b = bp[nt * 64];
      acc[nt] = __builtin_amdgcn_mfma_f32_16x16x32_f16(a, b, acc[nt], 0, 0, 0);
    }
  }
  __syncthreads();  // all waves done reading sA -> safe to alias

  float* sG = reinterpret_cast<float*>(sA);
  float* sS = sG + 64 * 128;
#pragma unroll
  for (int nt = 0; nt < 8; ++nt) {
    int col = nt * 16 + col16;
    float bb = bj[col];
#pragma unroll
    for (int i = 0; i < 4; ++i) {
      int lr = w * 16 + kgrp * 4 + i;
      sG[lr * 128 + col] = fmaxf(acc[nt][i] + bb, 0.f);
    }
  }
  __syncthreads();

  const int m = t & 63, grp = t >> 6;
  float a2[16];
#pragma unroll
  for (int i = 0; i < 16; ++i) a2[i] = b1p[m];
#pragma unroll 4
  for (int k = 0; k < 128; ++k) {
    float wv = W1p[(size_t)k * 64 + m];
#pragma unroll
    for (int i = 0; i < 16; ++i) a2[i] += sG[(grp * 16 + i) * 128 + k] * wv;
  }
#pragma unroll
  for (int i = 0; i < 16; ++i) sS[(grp * 16 + i) * 64 + m] = fmaxf(a2[i], 0.f);
  __syncthreads();

  if (t < 64) {
    int row = base + t;
    if (row < N) {
      float s = b2p[0];
#pragma unroll 8
      for (int mm = 0; mm < 64; ++mm) s += sS[t * 64 + mm] * W2p[mm];
      outp[row] = s;
    }
  }
}

// ---------------------------------------------------------------------------
extern "C" void kernel_launch(void* const* d_in, const int* in_sizes, int n_in,
                              void* d_out, int out_size, void* d_ws, size_t ws_size,
                              hipStream_t stream) {
  const float* x      = (const float*)d_in[0];
  const int*   ei     = (const int*)d_in[1];
  const float* eattr  = (const float*)d_in[2];
  const float* W_in   = (const float*)d_in[3];
  const float* b_in   = (const float*)d_in[4];
  const float* W_jump = (const float*)d_in[5];
  const float* b_jump = (const float*)d_in[6];
  const float* W1     = (const float*)d_in[7];
  const float* b1     = (const float*)d_in[8];
  const float* W2     = (const float*)d_in[9];
  const float* b2     = (const float*)d_in[10];
  const float* Wn[3] = {(const float*)d_in[11], (const float*)d_in[15], (const float*)d_in[19]};
  const float* Ws[3] = {(const float*)d_in[12], (const float*)d_in[16], (const float*)d_in[20]};
  const float* gm[3] = {(const float*)d_in[13], (const float*)d_in[17], (const float*)d_in[21]};
  const float* bt[3] = {(const float*)d_in[14], (const float*)d_in[18], (const float*)d_in[22]};

  const int N = in_sizes[0] / 4;
  const int E = in_sizes[2] / 2;
  const int* srcp = ei;
  const int* dstp = ei + (size_t)E;
  const size_t nh = (size_t)N * HDIM;
  const int M = 16 * N;                       // bucketed count entries
  const int nch = (M + 2047) / 2048;          // scan chunks (<=1024)

  // --- workspace carve-up (256B aligned blocks) ---
  char* wsb = (char*)d_ws;
  size_t off = 0;
  auto carve = [&](size_t bytes) -> void* {
    void* p = wsb + off;
    off = (off + bytes + 255) & ~(size_t)255;
    return p;
  };
  _Float16* h1   = (_Float16*)carve(nh * 2);
  _Float16* h2   = (_Float16*)carve(nh * 2);
  _Float16* h3   = (_Float16*)carve(nh * 2);
  _Float16* outh = (_Float16*)carve(nh * 2);
  float*    aggx = (float*)carve((size_t)N * 4 * 4);
  float*    eagg = (float*)carve((size_t)N * 2 * 4);
  int*      cnt  = (int*)carve((size_t)N * 4);
  int*      cnt16 = (int*)carve((size_t)M * 4);
  int*      rs16  = (int*)carve(((size_t)M + 16) * 4);
  int*      rank  = (int*)carve((size_t)E * 4);
  uint2*    cidx2 = (uint2*)carve((size_t)E * 8);
  int*      bsum = (int*)carve(4096);
  int*      boff = (int*)carve(4096);
  float*    bnstat = (float*)carve(3 * 256 * sizeof(float));
  _Float16* wpack  = (_Float16*)carve(147456 * 2);

  // --- bucketed CSR build + weight pack (layer-invariant) ---
  hipMemsetAsync(cnt16, 0, (size_t)M * sizeof(int), stream);
  hipMemsetAsync(bnstat, 0, 3 * 256 * sizeof(float), stream);
  count_kernel<<<(E + 255) / 256, 256, 0, stream>>>(srcp, dstp, cnt16, rank, E);
  pack_weights_kernel<<<(147456 + 255) / 256, 256, 0, stream>>>(
      Wn[0], Ws[0], Wn[1], Ws[1], Wn[2], Ws[2], W_jump, wpack);
  scan_block_sum2048<<<nch, 256, 0, stream>>>(cnt16, bsum, M);
  scan_partials<<<1, 256, 0, stream>>>(bsum, boff, nch);
  scan_final2048<<<nch, 256, 0, stream>>>(cnt16, boff, rs16, M);
  rowmeta_kernel<<<(N + 255) / 256, 256, 0, stream>>>(rs16, cnt, N, E);
  fill_kernel<<<(E + 255) / 256, 256, 0, stream>>>(srcp, dstp, eattr, rs16, rank, cidx2, E);

  const int gemm_grid = (N + 63) / 64;
  const float invN = 1.0f / (float)N;

  // --- layer 0 (aggregation folded into x-space; eagg computed here) ---
  aggx_kernel<<<(N + 255) / 256, 256, 0, stream>>>(x, rs16, cnt, cidx2, aggx, eagg, N);
  sage_mfma_kernel<true><<<gemm_grid, 256, 0, stream>>>(
      aggx, x, nullptr, rs16, cidx2, W_in, b_in, eagg, cnt, wpack, Wn[0],
      outh, bnstat, N);
  bn_l2_kernel<<<(N + 3) / 4, 256, 0, stream>>>(outh, bnstat, gm[0], bt[0], invN, h1, N);

  // --- layers 1,2 (bucketed gather fused into sage staging) ---
  _Float16* hbuf[3] = {h1, h2, h3};
  for (int l = 1; l < 3; ++l) {
    sage_mfma_kernel<false><<<gemm_grid, 256, 0, stream>>>(
        nullptr, nullptr, hbuf[l - 1], rs16, cidx2, nullptr, nullptr, eagg, cnt,
        wpack + (size_t)l * 32768, Wn[l], outh, bnstat + 256 * l, N);
    bn_l2_kernel<<<(N + 3) / 4, 256, 0, stream>>>(outh, bnstat + 256 * l,
                                                  gm[l], bt[l], invN, hbuf[l], N);
  }

  jump_mfma_kernel<<<gemm_grid, 256, 0, stream>>>(h1, h2, h3, wpack + 98304, b_jump,
                                                  W1, b1, W2, b2, (float*)d_out, N);
}

// Round 10
// 556.634 us; speedup vs baseline: 1.2762x; 1.2762x over previous
//
#include <hip/hip_runtime.h>

// ---------------------------------------------------------------------------
// GNN forward (GraphSAGE x3 + jump + scorer), N=100000, E=1600000, H=128.
// Round 10: r5 structure (best: 591us) + transaction-coalesced gather:
// the 4 lanes of a row-quad read CONTIGUOUS 16B pieces of each 64B line
// (addr = n*256 + j*64 + o*16) instead of 64B-strided quarters -> each
// instruction consumes whole lines (4x fewer transactions). 4-deep unroll.
// ---------------------------------------------------------------------------

#define HDIM 128

using f16x8 = __attribute__((ext_vector_type(8))) _Float16;
using f32x4 = __attribute__((ext_vector_type(4))) float;

__device__ inline unsigned pack_f16x2(float a, float b) {
  _Float16 ha = (_Float16)a, hb = (_Float16)b;
  unsigned short ua = __builtin_bit_cast(unsigned short, ha);
  unsigned short ub = __builtin_bit_cast(unsigned short, hb);
  return (unsigned)ua | ((unsigned)ub << 16);
}
__device__ inline float2 unpack_f16x2(unsigned u) {
  _Float16 lo = __builtin_bit_cast(_Float16, (unsigned short)(u & 0xffffu));
  _Float16 hi = __builtin_bit_cast(_Float16, (unsigned short)(u >> 16));
  return make_float2((float)lo, (float)hi);
}

// --- in-degree count; atomic return value IS the edge's intra-row rank -----
__global__ __launch_bounds__(256) void count_kernel(
    const int* __restrict__ dst, int* __restrict__ cnt,
    int* __restrict__ rank, int E) {
  int e = blockIdx.x * 256 + threadIdx.x;
  if (e >= E) return;
  rank[e] = atomicAdd(&cnt[dst[e]], 1);
}

// --- scan stage A ----------------------------------------------------------
__global__ __launch_bounds__(128) void scan_block_sum(
    const int* __restrict__ cnt, int* __restrict__ bsum, int N) {
  __shared__ int sd[128];
  int t = threadIdx.x;
  int i = blockIdx.x * 128 + t;
  sd[t] = (i < N) ? cnt[i] : 0;
  __syncthreads();
  for (int off = 64; off > 0; off >>= 1) {
    if (t < off) sd[t] += sd[t + off];
    __syncthreads();
  }
  if (t == 0) bsum[blockIdx.x] = sd[0];
}

// --- scan stage B ----------------------------------------------------------
__global__ __launch_bounds__(256) void scan_partials(
    const int* __restrict__ bsum, int* __restrict__ boff, int nch) {
  __shared__ int sd[256];
  int t = threadIdx.x;
  int base = t * 4;
  int v0 = (base + 0 < nch) ? bsum[base + 0] : 0;
  int v1 = (base + 1 < nch) ? bsum[base + 1] : 0;
  int v2 = (base + 2 < nch) ? bsum[base + 2] : 0;
  int v3 = (base + 3 < nch) ? bsum[base + 3] : 0;
  sd[t] = v0 + v1 + v2 + v3;
  __syncthreads();
  for (int off = 1; off < 256; off <<= 1) {
    int x = sd[t];
    int y = (t >= off) ? sd[t - off] : 0;
    __syncthreads();
    sd[t] = x + y;
    __syncthreads();
  }
  int run = (t == 0) ? 0 : sd[t - 1];
  if (base + 0 < nch) boff[base + 0] = run; run += v0;
  if (base + 1 < nch) boff[base + 1] = run; run += v1;
  if (base + 2 < nch) boff[base + 2] = run; run += v2;
  if (base + 3 < nch) boff[base + 3] = run;
}

// --- scan stage C ----------------------------------------------------------
__global__ __launch_bounds__(128) void scan_final(
    const int* __restrict__ cnt, const int* __restrict__ boff,
    int* __restrict__ rs, int N) {
  __shared__ int sd[128];
  int t = threadIdx.x, b = blockIdx.x;
  int i = b * 128 + t;
  int v = (i < N) ? cnt[i] : 0;
  sd[t] = v;
  __syncthreads();
  for (int off = 1; off < 128; off <<= 1) {
    int x = sd[t];
    int y = (t >= off) ? sd[t - off] : 0;
    __syncthreads();
    sd[t] = x + y;
    __syncthreads();
  }
  if (i < N) rs[i] = boff[b] + ((t == 0) ? 0 : sd[t - 1]);
}

// --- CSR fill, NO atomics: pos = rowstart[dst] + rank ----------------------
__global__ __launch_bounds__(256) void fill_kernel(
    const int* __restrict__ src, const int* __restrict__ dst,
    const float* __restrict__ ea, const int* __restrict__ rs,
    const int* __restrict__ rank, uint2* __restrict__ cidx2, int E) {
  int e = blockIdx.x * 256 + threadIdx.x;
  if (e >= E) return;
  int d = dst[e];
  float2 v = *reinterpret_cast<const float2*>(&ea[2 * (size_t)e]);
  int pos = rs[d] + rank[e];
  cidx2[pos] = make_uint2((unsigned)src[e], pack_f16x2(v.x, v.y));
}

// --- layer-0 x-space aggregation + edge-attr sum ---------------------------
__global__ __launch_bounds__(256) void aggx_kernel(
    const float* __restrict__ x, const int* __restrict__ rs,
    const int* __restrict__ cnt, const uint2* __restrict__ cidx2,
    float* __restrict__ aggx, float* __restrict__ eagg, int N) {
  int i = blockIdx.x * 256 + threadIdx.x;
  if (i >= N) return;
  float4 a = *reinterpret_cast<const float4*>(&x[(size_t)i * 4]);
  float4 b = make_float4(0.f, 0.f, 0.f, 0.f);
  float e0 = 0.f, e1 = 0.f, f0 = 0.f, f1 = 0.f;
  int p = rs[i], e = p + cnt[i];
  for (; p + 1 < e; p += 2) {
    uint2 c0 = cidx2[p], c1 = cidx2[p + 1];
    float4 v0 = *reinterpret_cast<const float4*>(&x[(size_t)c0.x * 4]);
    float4 v1 = *reinterpret_cast<const float4*>(&x[(size_t)c1.x * 4]);
    float2 u0 = unpack_f16x2(c0.y);
    float2 u1 = unpack_f16x2(c1.y);
    a.x += v0.x; a.y += v0.y; a.z += v0.z; a.w += v0.w;
    b.x += v1.x; b.y += v1.y; b.z += v1.z; b.w += v1.w;
    e0 += u0.x; e1 += u0.y;
    f0 += u1.x; f1 += u1.y;
  }
  if (p < e) {
    uint2 c0 = cidx2[p];
    float4 v0 = *reinterpret_cast<const float4*>(&x[(size_t)c0.x * 4]);
    float2 u0 = unpack_f16x2(c0.y);
    a.x += v0.x; a.y += v0.y; a.z += v0.z; a.w += v0.w;
    e0 += u0.x; e1 += u0.y;
  }
  a.x += b.x; a.y += b.y; a.z += b.z; a.w += b.w;
  *reinterpret_cast<float4*>(&aggx[(size_t)i * 4]) = a;
  eagg[2 * (size_t)i + 0] = e0 + f0;
  eagg[2 * (size_t)i + 1] = e1 + f1;
}

// --- pack GEMM weights into MFMA-frag-contiguous f16 layout ----------------
__global__ __launch_bounds__(256) void pack_weights_kernel(
    const float* __restrict__ Wn0, const float* __restrict__ Ws0,
    const float* __restrict__ Wn1, const float* __restrict__ Ws1,
    const float* __restrict__ Wn2, const float* __restrict__ Ws2,
    const float* __restrict__ Wj, _Float16* __restrict__ outp) {
  int i = blockIdx.x * 256 + threadIdx.x;
  if (i >= 147456) return;
  int j = i & 7, lane = (i >> 3) & 63;
  float v;
  if (i < 98304) {
    int l = i >> 15;
    int r = i & 32767;
    int nt = (r >> 9) & 7, kt = r >> 12;
    int k = kt * 32 + (lane >> 4) * 8 + j;
    int n = nt * 16 + (lane & 15);
    const float* Wn = (l == 0) ? Wn0 : (l == 1) ? Wn1 : Wn2;
    const float* Ws = (l == 0) ? Ws0 : (l == 1) ? Ws1 : Ws2;
    v = (k < 128) ? Wn[(size_t)k * HDIM + n] : Ws[(size_t)(k - 128) * HDIM + n];
  } else {
    int r = i - 98304;
    int nt = (r >> 9) & 7, kt = r >> 12;  // kt 0..11
    int k = kt * 32 + (lane >> 4) * 8 + j;
    int n = nt * 16 + (lane & 15);
    v = Wj[(size_t)k * HDIM + n];
  }
  outp[i] = (_Float16)v;
}

// --- fused SAGE layer on MFMA (gather fused for L != 0) --------------------
// Block: 64 rows, 4 waves; wave w owns rows w*16..w*16+15, all 128 cols.
// Gather layout (L!=0): row r <- lanes 4r..4r+3; lane offset o=t&3 reads
// CONTIGUOUS 16B at n*256 + j*64 + o*16 (full-line consumption).
// Lane (r,o) accumulates feature chunks k8 = o + j*4 (j=0..3).
template <bool L0>
__global__ __launch_bounds__(256) void sage_mfma_kernel(
    const float* __restrict__ A0f, const float* __restrict__ A1f,
    const _Float16* __restrict__ Hprev, const int* __restrict__ rs,
    const uint2* __restrict__ cidx2,
    const float* __restrict__ Wi, const float* __restrict__ bi,
    const float* __restrict__ eagg, const int* __restrict__ cnt,
    const _Float16* __restrict__ Bp, const float* __restrict__ Wn,
    _Float16* __restrict__ outh, float* __restrict__ bnstat, int N) {
  __shared__ _Float16 sA[64 * 256];  // 32 KB, XOR-swizzled rows
  __shared__ float sE[128];          // e0,e1 per row (pre-scaled)
  __shared__ float sBNs[4][128];
  __shared__ float sBNq[4][128];
  const int t = threadIdx.x;
  const int base = blockIdx.x * 64;

  if (t < 64) {
    int grow = base + t;
    float e0 = 0.f, e1 = 0.f;
    if (grow < N) {
      float inv = 1.0f / ((float)cnt[grow] + 1.0f);
      e0 = eagg[2 * (size_t)grow] * inv;
      e1 = eagg[2 * (size_t)grow + 1] * inv;
    }
    sE[2 * t] = e0;
    sE[2 * t + 1] = e1;
  }

  if (L0) {
    // stage A tile from x-space projections
#pragma unroll
    for (int it = 0; it < 8; ++it) {
      int c = t + it * 256;
      int row = c >> 5, k8 = c & 31;
      int grow = base + row;
      f16x8 hv = {};
      if (grow < N) {
        float inv = 1.0f / ((float)cnt[grow] + 1.0f);
        float scale = (k8 < 16) ? inv : 1.0f;
        const float* rp = (k8 < 16) ? &A0f[(size_t)grow * 4] : &A1f[(size_t)grow * 4];
        float4 r = *reinterpret_cast<const float4*>(rp);
        int col0 = (k8 & 15) * 8;
#pragma unroll
        for (int jj = 0; jj < 8; ++jj) {
          int col = col0 + jj;
          hv[jj] = (_Float16)(bi[col] + scale * (r.x * Wi[col] + r.y * Wi[HDIM + col] +
                                                 r.z * Wi[2 * HDIM + col] + r.w * Wi[3 * HDIM + col]));
        }
      }
      int byte = (row * 512 + k8 * 16) ^ ((row & 7) << 4);
      *reinterpret_cast<f16x8*>(reinterpret_cast<char*>(sA) + byte) = hv;
    }
  } else {
    // fused gather, line-coalesced: thread t -> row t>>2, lane offset o=t&3
    const int row = t >> 2, o = t & 3;
    const int grow = base + row;
    float acc[32];
#pragma unroll
    for (int c = 0; c < 32; ++c) acc[c] = 0.f;
    f16x8 selfv[4] = {};
    if (grow < N) {
      const char* selfrow = reinterpret_cast<const char*>(Hprev + (size_t)grow * HDIM);
#pragma unroll
      for (int j = 0; j < 4; ++j) {
        selfv[j] = *reinterpret_cast<const f16x8*>(selfrow + j * 64 + o * 16);
#pragma unroll
        for (int jj = 0; jj < 8; ++jj) acc[j * 8 + jj] = (float)selfv[j][jj];
      }
      int p = rs[grow];
      const int cn = cnt[grow];
      int e = p + cn;
      for (; p + 3 < e; p += 4) {
        uint2 q0 = cidx2[p], q1 = cidx2[p + 1], q2 = cidx2[p + 2], q3 = cidx2[p + 3];
        const char* m0 = reinterpret_cast<const char*>(Hprev + (size_t)q0.x * HDIM) + o * 16;
        const char* m1 = reinterpret_cast<const char*>(Hprev + (size_t)q1.x * HDIM) + o * 16;
        const char* m2 = reinterpret_cast<const char*>(Hprev + (size_t)q2.x * HDIM) + o * 16;
        const char* m3 = reinterpret_cast<const char*>(Hprev + (size_t)q3.x * HDIM) + o * 16;
        f16x8 c0[4], c1[4], c2[4], c3[4];
#pragma unroll
        for (int j = 0; j < 4; ++j) c0[j] = *reinterpret_cast<const f16x8*>(m0 + j * 64);
#pragma unroll
        for (int j = 0; j < 4; ++j) c1[j] = *reinterpret_cast<const f16x8*>(m1 + j * 64);
#pragma unroll
        for (int j = 0; j < 4; ++j) c2[j] = *reinterpret_cast<const f16x8*>(m2 + j * 64);
#pragma unroll
        for (int j = 0; j < 4; ++j) c3[j] = *reinterpret_cast<const f16x8*>(m3 + j * 64);
#pragma unroll
        for (int j = 0; j < 4; ++j)
#pragma unroll
          for (int jj = 0; jj < 8; ++jj)
            acc[j * 8 + jj] += ((float)c0[j][jj] + (float)c1[j][jj]) +
                               ((float)c2[j][jj] + (float)c3[j][jj]);
      }
      for (; p < e; ++p) {
        uint2 q0 = cidx2[p];
        const char* m0 = reinterpret_cast<const char*>(Hprev + (size_t)q0.x * HDIM) + o * 16;
#pragma unroll
        for (int j = 0; j < 4; ++j) {
          f16x8 c0 = *reinterpret_cast<const f16x8*>(m0 + j * 64);
#pragma unroll
          for (int jj = 0; jj < 8; ++jj) acc[j * 8 + jj] += (float)c0[jj];
        }
      }
      float inv = 1.0f / ((float)cn + 1.0f);
#pragma unroll
      for (int c = 0; c < 32; ++c) acc[c] *= inv;
    }
    const int swz = (row & 7) << 4;
#pragma unroll
    for (int j = 0; j < 4; ++j) {
      f16x8 av;
#pragma unroll
      for (int jj = 0; jj < 8; ++jj) av[jj] = (_Float16)acc[j * 8 + jj];
      int k8a = o + j * 4;                 // feature chunk (j*64+o*16 bytes)/16
      *reinterpret_cast<f16x8*>(reinterpret_cast<char*>(sA) +
                                ((row * 512 + k8a * 16) ^ swz)) = av;
      int k8h = 16 + o + j * 4;
      *reinterpret_cast<f16x8*>(reinterpret_cast<char*>(sA) +
                                ((row * 512 + k8h * 16) ^ swz)) = selfv[j];
    }
  }
  __syncthreads();

  const int lane = t & 63;
  const int w = t >> 6;
  const int col16 = lane & 15;
  const int kgrp = lane >> 4;
  f32x4 acc[8];
#pragma unroll
  for (int nt = 0; nt < 8; ++nt) acc[nt] = (f32x4){0.f, 0.f, 0.f, 0.f};

  const int arow = w * 16 + col16;
  const int aswz = (arow & 7) << 4;
#pragma unroll
  for (int kt = 0; kt < 8; ++kt) {
    int abyte = (arow * 512 + kt * 64 + kgrp * 16) ^ aswz;
    f16x8 a = *reinterpret_cast<const f16x8*>(reinterpret_cast<const char*>(sA) + abyte);
    const f16x8* bp = reinterpret_cast<const f16x8*>(Bp) + (size_t)kt * 512 + lane;
#pragma unroll
    for (int nt = 0; nt < 8; ++nt) {
      f16x8 b = bp[nt * 64];
      acc[nt] = __builtin_amdgcn_mfma_f32_16x16x32_f16(a, b, acc[nt], 0, 0, 0);
    }
  }

  // epilogue: edge-attr rank-2 update + relu + f16 store + BN partials
#pragma unroll
  for (int nt = 0; nt < 8; ++nt) {
    int col = nt * 16 + col16;
    float we0 = Wn[(size_t)128 * HDIM + col];
    float we1 = Wn[(size_t)129 * HDIM + col];
    float s = 0.f, q = 0.f;
#pragma unroll
    for (int i = 0; i < 4; ++i) {
      int lr = w * 16 + kgrp * 4 + i;
      int row = base + lr;
      if (row < N) {
        float v = acc[nt][i] + sE[2 * lr] * we0 + sE[2 * lr + 1] * we1;
        v = fmaxf(v, 0.f);
        outh[(size_t)row * HDIM + col] = (_Float16)v;
        s += v;
        q += v * v;
      }
    }
    s += __shfl_xor(s, 16, 64);
    s += __shfl_xor(s, 32, 64);
    q += __shfl_xor(q, 16, 64);
    q += __shfl_xor(q, 32, 64);
    if (lane < 16) {
      sBNs[w][col] = s;
      sBNq[w][col] = q;
    }
  }
  __syncthreads();
  if (t < 128) {
    float s = sBNs[0][t] + sBNs[1][t] + sBNs[2][t] + sBNs[3][t];
    float q = sBNq[0][t] + sBNq[1][t] + sBNq[2][t] + sBNq[3][t];
    atomicAdd(&bnstat[t], s);
    atomicAdd(&bnstat[HDIM + t], q);
  }
}

// --- BN finalize (in-block) + apply + L2 normalize: f16 in, f16 out --------
__global__ __launch_bounds__(256) void bn_l2_kernel(
    const _Float16* __restrict__ outh, const float* __restrict__ stat,
    const float* __restrict__ gamma, const float* __restrict__ beta,
    float invN, _Float16* __restrict__ h, int N) {
  __shared__ float sAB[256];
  int t = threadIdx.x;
  if (t < 128) {
    float mean = stat[t] * invN;
    float var = stat[128 + t] * invN - mean * mean;
    float A = gamma[t] / sqrtf(var + 1e-5f);
    sAB[t] = A;
    sAB[128 + t] = beta[t] - mean * A;
  }
  __syncthreads();
  int i = blockIdx.x * 4 + (t >> 6);
  if (i >= N) return;
  int lane = t & 63;
  unsigned u = (reinterpret_cast<const unsigned*>(outh + (size_t)i * HDIM))[lane];
  float2 v = unpack_f16x2(u);
  float A0 = sAB[lane * 2 + 0], A1 = sAB[lane * 2 + 1];
  float B0 = sAB[128 + lane * 2 + 0], B1 = sAB[128 + lane * 2 + 1];
  float y0 = v.x * A0 + B0;
  float y1 = v.y * A1 + B1;
  float s = y0 * y0 + y1 * y1;
#pragma unroll
  for (int m = 32; m > 0; m >>= 1) s += __shfl_xor(s, m, 64);
  float inv = 1.0f / fmaxf(sqrtf(s), 1e-12f);
  (reinterpret_cast<unsigned*>(h + (size_t)i * HDIM))[lane] =
      pack_f16x2(y0 * inv, y1 * inv);
}

// --- jump GEMM (MFMA, K=384, f16 h inputs) + scorer MLP --------------------
__global__ __launch_bounds__(256) void jump_mfma_kernel(
    const _Float16* __restrict__ h1, const _Float16* __restrict__ h2,
    const _Float16* __restrict__ h3, const _Float16* __restrict__ Bp,
    const float* __restrict__ bj, const float* __restrict__ W1p,
    const float* __restrict__ b1p, const float* __restrict__ W2p,
    const float* __restrict__ b2p, float* __restrict__ outp, int N) {
  __shared__ _Float16 sA[64 * 384];  // 48 KB; reused: sG[64*128] f32 + sS[64*64] f32
  const int t = threadIdx.x;
  const int base = blockIdx.x * 64;

  const _Float16* hs[3] = {h1, h2, h3};
#pragma unroll
  for (int it = 0; it < 12; ++it) {
    int c = t + it * 256;
    int row = c / 48, k8 = c % 48;
    int grow = base + row;
    f16x8 hv = {};
    if (grow < N)
      hv = (reinterpret_cast<const f16x8*>(hs[k8 >> 4] + (size_t)grow * HDIM))[k8 & 15];
    int byte = (row * 768 + k8 * 16) ^ ((row & 7) << 4);
    *reinterpret_cast<f16x8*>(reinterpret_cast<char*>(sA) + byte) = hv;
  }
  __syncthreads();

  const int lane = t & 63;
  const int w = t >> 6;
  const int col16 = lane & 15;
  const int kgrp = lane >> 4;
  f32x4 acc[8];
#pragma unroll
  for (int nt = 0; nt < 8; ++nt) acc[nt] = (f32x4){0.f, 0.f, 0.f, 0.f};

  const int arow = w * 16 + col16;
  const int aswz = (arow & 7) << 4;
#pragma unroll
  for (int kt = 0; kt < 12; ++kt) {
    int abyte = (arow * 768 + kt * 64 + kgrp * 16) ^ aswz;
    f16x8 a = *reinterpret_cast<const f16x8*>(reinterpret_cast<const char*>(sA) + abyte);
    const f16x8* bp = reinterpret_cast<const f16x8*>(Bp) + (size_t)kt * 512 + lane;
#pragma unroll
    for (int nt = 0; nt < 8; ++nt) {
      f16x8 b = bp[nt * 64];
      acc[nt] = __builtin_amdgcn_mfma_f32_16x16x32_f16(a, b, acc[nt], 0, 0, 0);
    }
  }
  __syncthreads();  // all waves done reading sA -> safe to alias

  float* sG = reinterpret_cast<float*>(sA);
  float* sS = sG + 64 * 128;
#pragma unroll
  for (int nt = 0; nt < 8; ++nt) {
    int col = nt * 16 + col16;
    float bb = bj[col];
#pragma unroll
    for (int i = 0; i < 4; ++i) {
      int lr = w * 16 + kgrp * 4 + i;
      sG[lr * 128 + col] = fmaxf(acc[nt][i] + bb, 0.f);
    }
  }
  __syncthreads();

  const int m = t & 63, grp = t >> 6;
  float a2[16];
#pragma unroll
  for (int i = 0; i < 16; ++i) a2[i] = b1p[m];
#pragma unroll 4
  for (int k = 0; k < 128; ++k) {
    float wv = W1p[(size_t)k * 64 + m];
#pragma unroll
    for (int i = 0; i < 16; ++i) a2[i] += sG[(grp * 16 + i) * 128 + k] * wv;
  }
#pragma unroll
  for (int i = 0; i < 16; ++i) sS[(grp * 16 + i) * 64 + m] = fmaxf(a2[i], 0.f);
  __syncthreads();

  if (t < 64) {
    int row = base + t;
    if (row < N) {
      float s = b2p[0];
#pragma unroll 8
      for (int mm = 0; mm < 64; ++mm) s += sS[t * 64 + mm] * W2p[mm];
      outp[row] = s;
    }
  }
}

// ---------------------------------------------------------------------------
extern "C" void kernel_launch(void* const* d_in, const int* in_sizes, int n_in,
                              void* d_out, int out_size, void* d_ws, size_t ws_size,
                              hipStream_t stream) {
  const float* x      = (const float*)d_in[0];
  const int*   ei     = (const int*)d_in[1];
  const float* eattr  = (const float*)d_in[2];
  const float* W_in   = (const float*)d_in[3];
  const float* b_in   = (const float*)d_in[4];
  const float* W_jump = (const float*)d_in[5];
  const float* b_jump = (const float*)d_in[6];
  const float* W1     = (const float*)d_in[7];
  const float* b1     = (const float*)d_in[8];
  const float* W2     = (const float*)d_in[9];
  const float* b2     = (const float*)d_in[10];
  const float* Wn[3] = {(const float*)d_in[11], (const float*)d_in[15], (const float*)d_in[19]};
  const float* Ws[3] = {(const float*)d_in[12], (const float*)d_in[16], (const float*)d_in[20]};
  const float* gm[3] = {(const float*)d_in[13], (const float*)d_in[17], (const float*)d_in[21]};
  const float* bt[3] = {(const float*)d_in[14], (const float*)d_in[18], (const float*)d_in[22]};

  const int N = in_sizes[0] / 4;
  const int E = in_sizes[2] / 2;
  const int* srcp = ei;
  const int* dstp = ei + (size_t)E;
  const int nch = (N + 127) / 128;
  const size_t nh = (size_t)N * HDIM;

  // --- workspace carve-up (256B aligned blocks) ---
  char* wsb = (char*)d_ws;
  size_t off = 0;
  auto carve = [&](size_t bytes) -> void* {
    void* p = wsb + off;
    off = (off + bytes + 255) & ~(size_t)255;
    return p;
  };
  _Float16* h1   = (_Float16*)carve(nh * 2);
  _Float16* h2   = (_Float16*)carve(nh * 2);
  _Float16* h3   = (_Float16*)carve(nh * 2);
  _Float16* outh = (_Float16*)carve(nh * 2);
  float*    aggx = (float*)carve((size_t)N * 4 * 4);
  float*    eagg = (float*)carve((size_t)N * 2 * 4);
  int*      cnt  = (int*)carve((size_t)N * 4);
  int*      rowstart = (int*)carve((size_t)N * 4);
  int*      rank     = (int*)carve((size_t)E * 4);
  uint2*    cidx2    = (uint2*)carve((size_t)E * 8);
  int*      bsum = (int*)carve(4096);
  int*      boff = (int*)carve(4096);
  float*    bnstat = (float*)carve(3 * 256 * sizeof(float));
  _Float16* wpack  = (_Float16*)carve(147456 * 2);

  // --- CSR build + weight pack (layer-invariant) ---
  hipMemsetAsync(cnt, 0, (size_t)N * sizeof(int), stream);
  hipMemsetAsync(bnstat, 0, 3 * 256 * sizeof(float), stream);
  count_kernel<<<(E + 255) / 256, 256, 0, stream>>>(dstp, cnt, rank, E);
  pack_weights_kernel<<<(147456 + 255) / 256, 256, 0, stream>>>(
      Wn[0], Ws[0], Wn[1], Ws[1], Wn[2], Ws[2], W_jump, wpack);
  scan_block_sum<<<nch, 128, 0, stream>>>(cnt, bsum, N);
  scan_partials<<<1, 256, 0, stream>>>(bsum, boff, nch);
  scan_final<<<nch, 128, 0, stream>>>(cnt, boff, rowstart, N);
  fill_kernel<<<(E + 255) / 256, 256, 0, stream>>>(srcp, dstp, eattr, rowstart, rank, cidx2, E);

  const int gemm_grid = (N + 63) / 64;
  const float invN = 1.0f / (float)N;

  // --- layer 0 (aggregation folded into x-space; eagg computed here) ---
  aggx_kernel<<<(N + 255) / 256, 256, 0, stream>>>(x, rowstart, cnt, cidx2, aggx, eagg, N);
  sage_mfma_kernel<true><<<gemm_grid, 256, 0, stream>>>(
      aggx, x, nullptr, rowstart, cidx2, W_in, b_in, eagg, cnt, wpack, Wn[0],
      outh, bnstat, N);
  bn_l2_kernel<<<(N + 3) / 4, 256, 0, stream>>>(outh, bnstat, gm[0], bt[0], invN, h1, N);

  // --- layers 1,2 (gather fused into sage staging) ---
  _Float16* hbuf[3] = {h1, h2, h3};
  for (int l = 1; l < 3; ++l) {
    sage_mfma_kernel<false><<<gemm_grid, 256, 0, stream>>>(
        nullptr, nullptr, hbuf[l - 1], rowstart, cidx2, nullptr, nullptr, eagg, cnt,
        wpack + (size_t)l * 32768, Wn[l], outh, bnstat + 256 * l, N);
    bn_l2_kernel<<<(N + 3) / 4, 256, 0, stream>>>(outh, bnstat + 256 * l,
                                                  gm[l], bt[l], invN, hbuf[l], N);
  }

  jump_mfma_kernel<<<gemm_grid, 256, 0, stream>>>(h1, h2, h3, wpack + 98304, b_jump,
                                                  W1, b1, W2, b2, (float*)d_out, N);
}